// Round 1
// baseline (56.683 us; speedup 1.0000x reference)
//
#include <hip/hip_runtime.h>

// ---------------------------------------------------------------------------
// NewsEncoder: fold all linear ops into gather tables.
//   P_cat  [1000][16] = cat_emb @ cat_W
//   P_type [10][16]   = type_emb @ type_W
//   Q_cat  [1000][32] = P_cat @ w1_W[0:16]
//   Q_type [10][32]   = P_type @ w1_W[19:35]
//   c0     [32]       = 2*cat_b@w1_W[0:16] + type_b@w1_W[19:35] + w1_b
// Target row:  x_t = [P_cat[cat]+mean(P_cat[sub])+2*cat_b, sent, P_type[ty]+type_b]
// History row: x_h = Q_cat[cat]+mean(Q_cat[sub])+Q_type[ty]
//                    + sent@w1_W[16:19] + rt*w1_W[35] + sc*w1_W[36] + c0
// ---------------------------------------------------------------------------

#define OFF_PCAT  0
#define OFF_PTYPE 16000
#define OFF_QCAT  16384
#define OFF_QTYPE 48384
#define OFF_C0    48704

__device__ __forceinline__ float4 f4add(float4 a, float4 b) {
    return make_float4(a.x + b.x, a.y + b.y, a.z + b.z, a.w + b.w);
}
__device__ __forceinline__ float4 f4fma(float s, float4 a, float4 c) {
    // c + s*a
    return make_float4(fmaf(s, a.x, c.x), fmaf(s, a.y, c.y),
                       fmaf(s, a.z, c.z), fmaf(s, a.w, c.w));
}

// ---------------------------------------------------------------------------
// Kernel A: build tables in workspace. 8 blocks x 128 threads; thread = table row.
// ---------------------------------------------------------------------------
__global__ __launch_bounds__(128) void precompute_tables(
    const float* __restrict__ cat_emb, const float* __restrict__ cat_W,
    const float* __restrict__ cat_b,   const float* __restrict__ type_emb,
    const float* __restrict__ type_W,  const float* __restrict__ type_b,
    const float* __restrict__ w1_W,    const float* __restrict__ w1_b,
    float* __restrict__ ws)
{
    __shared__ float sWc[64 * 16];
    __shared__ float sWt[64 * 16];
    __shared__ float sW1[37 * 32];
    const int tid = threadIdx.x;
    for (int i = tid; i < 64 * 16; i += 128) sWc[i] = cat_W[i];
    for (int i = tid; i < 64 * 16; i += 128) sWt[i] = type_W[i];
    for (int i = tid; i < 37 * 32; i += 128) sW1[i] = w1_W[i];
    __syncthreads();

    const int r = blockIdx.x * 128 + tid;
    float* P_cat  = ws + OFF_PCAT;
    float* P_type = ws + OFF_PTYPE;
    float* Q_cat  = ws + OFF_QCAT;
    float* Q_type = ws + OFF_QTYPE;
    float* c0     = ws + OFF_C0;

    if (r < 1000) {
        float p[16];
#pragma unroll
        for (int k = 0; k < 16; ++k) p[k] = 0.f;
        const float4* er4 = (const float4*)(cat_emb + r * 64);
#pragma unroll 4
        for (int e4 = 0; e4 < 16; ++e4) {
            float4 ev = er4[e4];
            const float* wrow = sWc + e4 * 4 * 16;
#pragma unroll
            for (int k = 0; k < 16; ++k) p[k] = fmaf(ev.x, wrow[k], p[k]);
#pragma unroll
            for (int k = 0; k < 16; ++k) p[k] = fmaf(ev.y, wrow[16 + k], p[k]);
#pragma unroll
            for (int k = 0; k < 16; ++k) p[k] = fmaf(ev.z, wrow[32 + k], p[k]);
#pragma unroll
            for (int k = 0; k < 16; ++k) p[k] = fmaf(ev.w, wrow[48 + k], p[k]);
        }
        float q[32];
#pragma unroll
        for (int j = 0; j < 32; ++j) q[j] = 0.f;
#pragma unroll
        for (int k = 0; k < 16; ++k) {
            const float pk = p[k];
#pragma unroll
            for (int j = 0; j < 32; ++j) q[j] = fmaf(pk, sW1[k * 32 + j], q[j]);
        }
#pragma unroll
        for (int k = 0; k < 16; ++k) P_cat[r * 16 + k] = p[k];
#pragma unroll
        for (int j = 0; j < 32; ++j) Q_cat[r * 32 + j] = q[j];
    } else if (r < 1010) {
        const int tr = r - 1000;
        float p[16];
#pragma unroll
        for (int k = 0; k < 16; ++k) p[k] = 0.f;
        const float4* er4 = (const float4*)(type_emb + tr * 64);
#pragma unroll 4
        for (int e4 = 0; e4 < 16; ++e4) {
            float4 ev = er4[e4];
            const float* wrow = sWt + e4 * 4 * 16;
#pragma unroll
            for (int k = 0; k < 16; ++k) p[k] = fmaf(ev.x, wrow[k], p[k]);
#pragma unroll
            for (int k = 0; k < 16; ++k) p[k] = fmaf(ev.y, wrow[16 + k], p[k]);
#pragma unroll
            for (int k = 0; k < 16; ++k) p[k] = fmaf(ev.z, wrow[32 + k], p[k]);
#pragma unroll
            for (int k = 0; k < 16; ++k) p[k] = fmaf(ev.w, wrow[48 + k], p[k]);
        }
        float q[32];
#pragma unroll
        for (int j = 0; j < 32; ++j) q[j] = 0.f;
#pragma unroll
        for (int k = 0; k < 16; ++k) {
            const float pk = p[k];
#pragma unroll
            for (int j = 0; j < 32; ++j) q[j] = fmaf(pk, sW1[(19 + k) * 32 + j], q[j]);
        }
#pragma unroll
        for (int k = 0; k < 16; ++k) P_type[tr * 16 + k] = p[k];
#pragma unroll
        for (int j = 0; j < 32; ++j) Q_type[tr * 32 + j] = q[j];
    }

    if (blockIdx.x == 0 && tid < 32) {
        const int j = tid;
        float c = w1_b[j];
#pragma unroll
        for (int k = 0; k < 16; ++k) c = fmaf(2.f * cat_b[k], sW1[k * 32 + j], c);
#pragma unroll
        for (int k = 0; k < 16; ++k) c = fmaf(type_b[k], sW1[(19 + k) * 32 + j], c);
        c0[j] = c;
    }
}

// ---------------------------------------------------------------------------
// Kernel B: fused target + history. Blocks [0, tb) -> target, [tb, tb+hb) -> history.
// One thread per row; LDS-staged coalesced output.
// ---------------------------------------------------------------------------
__global__ __launch_bounds__(256, 4) void news_main(
    const int* __restrict__ cat_t, const int* __restrict__ sub_t,
    const int* __restrict__ sub_len_t, const float* __restrict__ sent_t,
    const int* __restrict__ type_t,
    const int* __restrict__ cat_h, const int* __restrict__ sub_h,
    const int* __restrict__ sub_len_h, const float* __restrict__ sent_h,
    const int* __restrict__ type_h,
    const float* __restrict__ rt_h, const float* __restrict__ sc_h,
    const float* __restrict__ cat_b, const float* __restrict__ type_b,
    const float* __restrict__ w1_W,
    const float* __restrict__ ws, float* __restrict__ out,
    int Nt, int Nh, int tb)
{
    __shared__ float stage[256 * 36];
    __shared__ float wl[6 * 32];

    const float4* P4  = (const float4*)(ws + OFF_PCAT);   // [1000][4]
    const float4* PT4 = (const float4*)(ws + OFF_PTYPE);  // [10][4]
    const float4* Q4  = (const float4*)(ws + OFF_QCAT);   // [1000][8]
    const float4* QT4 = (const float4*)(ws + OFF_QTYPE);  // [10][8]
    const float*  c0  = ws + OFF_C0;

    const int tid = threadIdx.x;
    const int b   = blockIdx.x;

    if (b < tb) {
        // ------------------------- target branch -------------------------
        const int n = b * 256 + tid;
        if (n < Nt) {
            const int cat = cat_t[n];
            const int ty  = type_t[n];
            int len = sub_len_t[n];
            if (len < 1) len = 1;
            const int4* sp = (const int4*)(sub_t + (size_t)n * 8);
            const int4 sa = sp[0];
            const int4 sb = sp[1];

            const float4* pc = P4 + cat * 4;
            float4 a0 = pc[0], a1 = pc[1], a2 = pc[2], a3 = pc[3];
            float4 s0 = make_float4(0, 0, 0, 0), s1 = s0, s2 = s0, s3 = s0;
#define GATH4(COND, V)                                             \
            if (COND) {                                            \
                const float4* pr = P4 + (V) * 4;                   \
                s0 = f4add(s0, pr[0]); s1 = f4add(s1, pr[1]);      \
                s2 = f4add(s2, pr[2]); s3 = f4add(s3, pr[3]);      \
            }
            GATH4(true,     sa.x)
            GATH4(len > 1,  sa.y)
            GATH4(len > 2,  sa.z)
            GATH4(len > 3,  sa.w)
            GATH4(len > 4,  sb.x)
            GATH4(len > 5,  sb.y)
            GATH4(len > 6,  sb.z)
            GATH4(len > 7,  sb.w)
#undef GATH4
            const float inv = 1.0f / (float)len;
            const float4* cb4 = (const float4*)cat_b;
            const float4* tb4 = (const float4*)type_b;
            a0 = f4fma(inv, s0, a0); a1 = f4fma(inv, s1, a1);
            a2 = f4fma(inv, s2, a2); a3 = f4fma(inv, s3, a3);
            a0 = f4fma(2.f, cb4[0], a0); a1 = f4fma(2.f, cb4[1], a1);
            a2 = f4fma(2.f, cb4[2], a2); a3 = f4fma(2.f, cb4[3], a3);
            const float4* pt = PT4 + ty * 4;
            float4 t0 = f4add(pt[0], tb4[0]);
            float4 t1 = f4add(pt[1], tb4[1]);
            float4 t2 = f4add(pt[2], tb4[2]);
            float4 t3 = f4add(pt[3], tb4[3]);

            float4* row4 = (float4*)(stage + tid * 36);
            row4[0] = a0; row4[1] = a1; row4[2] = a2; row4[3] = a3;
            row4[4] = t0; row4[5] = t1; row4[6] = t2; row4[7] = t3;
            float* row = stage + tid * 36;
            row[32] = sent_t[(size_t)n * 3 + 0];
            row[33] = sent_t[(size_t)n * 3 + 1];
            row[34] = sent_t[(size_t)n * 3 + 2];
        }
        __syncthreads();
        // coalesced copy out: out col j -> stage col (j<16: j, 16..18: 32+j-16, 19..34: j-3)
        int rows_this = Nt - b * 256;
        if (rows_this > 256) rows_this = 256;
        const int cnt = rows_this * 35;
        const size_t base = (size_t)b * 256 * 35;
        for (int i = tid; i < cnt; i += 256) {
            const int r2 = i / 35;
            const int c2 = i - r2 * 35;
            const int scol = (c2 < 16) ? c2 : ((c2 < 19) ? (16 + c2) - 0x0 - 0 + 16 : c2 - 3);
            // note: for 16<=c2<19 we want 32+(c2-16) = c2+16
            out[base + i] = stage[r2 * 36 + ((c2 >= 16 && c2 < 19) ? (c2 + 16) : scol)];
        }
    } else {
        // ------------------------- history branch -------------------------
        if (tid < 192) {
            const int rr = tid >> 5, cc = tid & 31;
            const int srow = (rr < 3) ? (16 + rr) : (35 + (rr - 3));  // 16,17,18,35,36
            wl[tid] = (rr < 5) ? w1_W[srow * 32 + cc] : c0[cc];
        }
        __syncthreads();
        const int b2 = b - tb;
        const int n = b2 * 256 + tid;
        if (n < Nh) {
            const int cat = cat_h[n];
            const int ty  = type_h[n];
            int len = sub_len_h[n];
            if (len < 1) len = 1;
            const int4* sp = (const int4*)(sub_h + (size_t)n * 8);
            const int4 sa = sp[0];
            const int4 sb = sp[1];

            const float4* qc = Q4 + cat * 8;
            float4 q0 = qc[0], q1 = qc[1], q2 = qc[2], q3 = qc[3];
            float4 q4 = qc[4], q5 = qc[5], q6 = qc[6], q7 = qc[7];
            float4 s0 = make_float4(0, 0, 0, 0), s1 = s0, s2 = s0, s3 = s0;
            float4 s4 = s0, s5 = s0, s6 = s0, s7 = s0;
#define GATH8(COND, V)                                              \
            if (COND) {                                             \
                const float4* pr = Q4 + (V) * 8;                    \
                s0 = f4add(s0, pr[0]); s1 = f4add(s1, pr[1]);       \
                s2 = f4add(s2, pr[2]); s3 = f4add(s3, pr[3]);       \
                s4 = f4add(s4, pr[4]); s5 = f4add(s5, pr[5]);       \
                s6 = f4add(s6, pr[6]); s7 = f4add(s7, pr[7]);       \
            }
            GATH8(true,     sa.x)
            GATH8(len > 1,  sa.y)
            GATH8(len > 2,  sa.z)
            GATH8(len > 3,  sa.w)
            GATH8(len > 4,  sb.x)
            GATH8(len > 5,  sb.y)
            GATH8(len > 6,  sb.z)
            GATH8(len > 7,  sb.w)
#undef GATH8
            const float inv = 1.0f / (float)len;
            q0 = f4fma(inv, s0, q0); q1 = f4fma(inv, s1, q1);
            q2 = f4fma(inv, s2, q2); q3 = f4fma(inv, s3, q3);
            q4 = f4fma(inv, s4, q4); q5 = f4fma(inv, s5, q5);
            q6 = f4fma(inv, s6, q6); q7 = f4fma(inv, s7, q7);
            const float4* qt = QT4 + ty * 8;
            q0 = f4add(q0, qt[0]); q1 = f4add(q1, qt[1]);
            q2 = f4add(q2, qt[2]); q3 = f4add(q3, qt[3]);
            q4 = f4add(q4, qt[4]); q5 = f4add(q5, qt[5]);
            q6 = f4add(q6, qt[6]); q7 = f4add(q7, qt[7]);

            const float se0 = sent_h[(size_t)n * 3 + 0];
            const float se1 = sent_h[(size_t)n * 3 + 1];
            const float se2 = sent_h[(size_t)n * 3 + 2];
            const float rtv = rt_h[n];
            const float scv = sc_h[n];
            const float4* wl4 = (const float4*)wl;
#define AXPYROW(S, R)                                                     \
            q0 = f4fma(S, wl4[(R) * 8 + 0], q0);                          \
            q1 = f4fma(S, wl4[(R) * 8 + 1], q1);                          \
            q2 = f4fma(S, wl4[(R) * 8 + 2], q2);                          \
            q3 = f4fma(S, wl4[(R) * 8 + 3], q3);                          \
            q4 = f4fma(S, wl4[(R) * 8 + 4], q4);                          \
            q5 = f4fma(S, wl4[(R) * 8 + 5], q5);                          \
            q6 = f4fma(S, wl4[(R) * 8 + 6], q6);                          \
            q7 = f4fma(S, wl4[(R) * 8 + 7], q7);
            AXPYROW(se0, 0)
            AXPYROW(se1, 1)
            AXPYROW(se2, 2)
            AXPYROW(rtv, 3)
            AXPYROW(scv, 4)
            AXPYROW(1.f, 5)
#undef AXPYROW
            float4* row4 = (float4*)(stage + tid * 36);
            row4[0] = q0; row4[1] = q1; row4[2] = q2; row4[3] = q3;
            row4[4] = q4; row4[5] = q5; row4[6] = q6; row4[7] = q7;
        }
        __syncthreads();
        int rows_this = Nh - b2 * 256;
        if (rows_this > 256) rows_this = 256;
        const int cnt = rows_this * 32;
        const size_t base = (size_t)Nt * 35 + (size_t)b2 * 256 * 32;
        for (int i = tid; i < cnt; i += 256) {
            out[base + i] = stage[(i >> 5) * 36 + (i & 31)];
        }
    }
}

extern "C" void kernel_launch(void* const* d_in, const int* in_sizes, int n_in,
                              void* d_out, int out_size, void* d_ws, size_t ws_size,
                              hipStream_t stream) {
    const int*   cat_t     = (const int*)d_in[0];
    const int*   sub_t     = (const int*)d_in[1];
    const int*   sub_len_t = (const int*)d_in[2];
    const float* sent_t    = (const float*)d_in[3];
    const int*   type_t    = (const int*)d_in[4];
    const int*   cat_h     = (const int*)d_in[5];
    const int*   sub_h     = (const int*)d_in[6];
    const int*   sub_len_h = (const int*)d_in[7];
    const float* sent_h    = (const float*)d_in[8];
    const int*   type_h    = (const int*)d_in[9];
    const float* rt_h      = (const float*)d_in[10];
    const float* sc_h      = (const float*)d_in[11];
    const float* cat_emb   = (const float*)d_in[12];
    const float* cat_W     = (const float*)d_in[13];
    const float* cat_b     = (const float*)d_in[14];
    const float* type_emb  = (const float*)d_in[15];
    const float* type_W    = (const float*)d_in[16];
    const float* type_b    = (const float*)d_in[17];
    const float* w1_W      = (const float*)d_in[18];
    const float* w1_b      = (const float*)d_in[19];

    float* ws  = (float*)d_ws;
    float* out = (float*)d_out;
    const int Nt = in_sizes[0];
    const int Nh = in_sizes[5];

    precompute_tables<<<8, 128, 0, stream>>>(cat_emb, cat_W, cat_b,
                                             type_emb, type_W, type_b,
                                             w1_W, w1_b, ws);

    const int tbn = (Nt + 255) / 256;
    const int hbn = (Nh + 255) / 256;
    news_main<<<tbn + hbn, 256, 0, stream>>>(
        cat_t, sub_t, sub_len_t, sent_t, type_t,
        cat_h, sub_h, sub_len_h, sent_h, type_h,
        rt_h, sc_h, cat_b, type_b, w1_W,
        ws, out, Nt, Nh, tbn);
}

// Round 2
// 46.113 us; speedup vs baseline: 1.2292x; 1.2292x over previous
//
#include <hip/hip_runtime.h>

// ---------------------------------------------------------------------------
// NewsEncoder: fold all linear ops into gather tables (in d_ws).
//   P_cat  [1000][16] = cat_emb @ cat_W
//   P_type [10][16]   = type_emb @ type_W
//   Q_cat  [1000][32] = P_cat @ w1_W[0:16]
//   Q_type [10][32]   = P_type @ w1_W[19:35]
//   c0     [32]       = 2*cat_b@w1_W[0:16] + type_b@w1_W[19:35] + w1_b
// Target row:  x_t = [P_cat[cat]+mean(P_cat[sub])+2*cat_b, sent, P_type[ty]+type_b]
// History row: x_h = Q_cat[cat]+mean(Q_cat[sub])+Q_type[ty]
//                    + sent@w1_W[16:19] + rt*w1_W[35] + sc*w1_W[36] + c0
//
// R1 -> R2: cooperative gathers. 8 lanes/row (history), 4 lanes/row (target):
// each lane owns one float4 of the table row -> gather instructions are fully
// coalesced (8 lines/wave instead of 64), 8x fewer VMEM instructions, direct
// coalesced float4 stores for history. LDS 37KB -> ~10KB for occupancy.
// ---------------------------------------------------------------------------

#define OFF_PCAT  0
#define OFF_PTYPE 16000
#define OFF_QCAT  16384
#define OFF_QTYPE 48384
#define OFF_C0    48704

__device__ __forceinline__ float4 f4add(float4 a, float4 b) {
    return make_float4(a.x + b.x, a.y + b.y, a.z + b.z, a.w + b.w);
}
__device__ __forceinline__ float4 f4fma(float s, float4 a, float4 c) {
    return make_float4(fmaf(s, a.x, c.x), fmaf(s, a.y, c.y),
                       fmaf(s, a.z, c.z), fmaf(s, a.w, c.w));
}

// ---------------------------------------------------------------------------
// Kernel A: build tables in workspace. 8 blocks x 128 threads; thread = row.
// ---------------------------------------------------------------------------
__global__ __launch_bounds__(128) void precompute_tables(
    const float* __restrict__ cat_emb, const float* __restrict__ cat_W,
    const float* __restrict__ cat_b,   const float* __restrict__ type_emb,
    const float* __restrict__ type_W,  const float* __restrict__ type_b,
    const float* __restrict__ w1_W,    const float* __restrict__ w1_b,
    float* __restrict__ ws)
{
    __shared__ float sWc[64 * 16];
    __shared__ float sWt[64 * 16];
    __shared__ float sW1[37 * 32];
    const int tid = threadIdx.x;
    for (int i = tid; i < 64 * 16; i += 128) sWc[i] = cat_W[i];
    for (int i = tid; i < 64 * 16; i += 128) sWt[i] = type_W[i];
    for (int i = tid; i < 37 * 32; i += 128) sW1[i] = w1_W[i];
    __syncthreads();

    const int r = blockIdx.x * 128 + tid;
    float* P_cat  = ws + OFF_PCAT;
    float* P_type = ws + OFF_PTYPE;
    float* Q_cat  = ws + OFF_QCAT;
    float* Q_type = ws + OFF_QTYPE;
    float* c0     = ws + OFF_C0;

    if (r < 1000) {
        float p[16];
#pragma unroll
        for (int k = 0; k < 16; ++k) p[k] = 0.f;
        const float4* er4 = (const float4*)(cat_emb + r * 64);
#pragma unroll 4
        for (int e4 = 0; e4 < 16; ++e4) {
            float4 ev = er4[e4];
            const float* wrow = sWc + e4 * 4 * 16;
#pragma unroll
            for (int k = 0; k < 16; ++k) p[k] = fmaf(ev.x, wrow[k], p[k]);
#pragma unroll
            for (int k = 0; k < 16; ++k) p[k] = fmaf(ev.y, wrow[16 + k], p[k]);
#pragma unroll
            for (int k = 0; k < 16; ++k) p[k] = fmaf(ev.z, wrow[32 + k], p[k]);
#pragma unroll
            for (int k = 0; k < 16; ++k) p[k] = fmaf(ev.w, wrow[48 + k], p[k]);
        }
        float q[32];
#pragma unroll
        for (int j = 0; j < 32; ++j) q[j] = 0.f;
#pragma unroll
        for (int k = 0; k < 16; ++k) {
            const float pk = p[k];
#pragma unroll
            for (int j = 0; j < 32; ++j) q[j] = fmaf(pk, sW1[k * 32 + j], q[j]);
        }
#pragma unroll
        for (int k = 0; k < 16; ++k) P_cat[r * 16 + k] = p[k];
#pragma unroll
        for (int j = 0; j < 32; ++j) Q_cat[r * 32 + j] = q[j];
    } else if (r < 1010) {
        const int tr = r - 1000;
        float p[16];
#pragma unroll
        for (int k = 0; k < 16; ++k) p[k] = 0.f;
        const float4* er4 = (const float4*)(type_emb + tr * 64);
#pragma unroll 4
        for (int e4 = 0; e4 < 16; ++e4) {
            float4 ev = er4[e4];
            const float* wrow = sWt + e4 * 4 * 16;
#pragma unroll
            for (int k = 0; k < 16; ++k) p[k] = fmaf(ev.x, wrow[k], p[k]);
#pragma unroll
            for (int k = 0; k < 16; ++k) p[k] = fmaf(ev.y, wrow[16 + k], p[k]);
#pragma unroll
            for (int k = 0; k < 16; ++k) p[k] = fmaf(ev.z, wrow[32 + k], p[k]);
#pragma unroll
            for (int k = 0; k < 16; ++k) p[k] = fmaf(ev.w, wrow[48 + k], p[k]);
        }
        float q[32];
#pragma unroll
        for (int j = 0; j < 32; ++j) q[j] = 0.f;
#pragma unroll
        for (int k = 0; k < 16; ++k) {
            const float pk = p[k];
#pragma unroll
            for (int j = 0; j < 32; ++j) q[j] = fmaf(pk, sW1[(19 + k) * 32 + j], q[j]);
        }
#pragma unroll
        for (int k = 0; k < 16; ++k) P_type[tr * 16 + k] = p[k];
#pragma unroll
        for (int j = 0; j < 32; ++j) Q_type[tr * 32 + j] = q[j];
    }

    if (blockIdx.x == 0 && tid < 32) {
        const int j = tid;
        float c = w1_b[j];
#pragma unroll
        for (int k = 0; k < 16; ++k) c = fmaf(2.f * cat_b[k], sW1[k * 32 + j], c);
#pragma unroll
        for (int k = 0; k < 16; ++k) c = fmaf(type_b[k], sW1[(19 + k) * 32 + j], c);
        c0[j] = c;
    }
}

// ---------------------------------------------------------------------------
// Kernel B: fused target + history.
//   blocks [0, tb):  target, 64 rows/block, 4 lanes/row, LDS-staged output
//   blocks [tb, ..): history, 32 rows/block, 8 lanes/row, direct f4 stores
// ---------------------------------------------------------------------------
__global__ __launch_bounds__(256, 8) void news_main(
    const int* __restrict__ cat_t, const int* __restrict__ sub_t,
    const int* __restrict__ sub_len_t, const float* __restrict__ sent_t,
    const int* __restrict__ type_t,
    const int* __restrict__ cat_h, const int* __restrict__ sub_h,
    const int* __restrict__ sub_len_h, const float* __restrict__ sent_h,
    const int* __restrict__ type_h,
    const float* __restrict__ rt_h, const float* __restrict__ sc_h,
    const float* __restrict__ cat_b, const float* __restrict__ type_b,
    const float* __restrict__ w1_W,
    const float* __restrict__ ws, float* __restrict__ out,
    int Nt, int Nh, int tb)
{
    __shared__ float stage[64 * 36];   // target out staging (9216 B)
    __shared__ float wl[6 * 32];       // history folded weights

    const float4* P4  = (const float4*)(ws + OFF_PCAT);   // [1000] rows of 4xf4
    const float4* PT4 = (const float4*)(ws + OFF_PTYPE);  // [10]   rows of 4xf4
    const float4* Q4  = (const float4*)(ws + OFF_QCAT);   // [1000] rows of 8xf4
    const float4* QT4 = (const float4*)(ws + OFF_QTYPE);  // [10]   rows of 8xf4
    const float*  c0  = ws + OFF_C0;

    const int tid = threadIdx.x;
    const int b   = blockIdx.x;

    if (b < tb) {
        // ------------------------- target branch -------------------------
        const int g  = tid >> 2;       // 0..63: row within block
        const int sl = tid & 3;        // lane's float4 slot within the 16-col row
        const int n  = b * 64 + g;
        if (n < Nt) {
            const int cat = cat_t[n];
            const int ty  = type_t[n];
            int len = sub_len_t[n];
            if (len < 1) len = 1;
            const int4* sp = (const int4*)(sub_t + (size_t)n * 8);
            const int4 sa = sp[0];
            const int4 sb = sp[1];

            float4 a = P4[cat * 4 + sl];
            float4 s = make_float4(0, 0, 0, 0);
            s = f4add(s, P4[sa.x * 4 + sl]);
            if (len > 1) s = f4add(s, P4[sa.y * 4 + sl]);
            if (len > 2) s = f4add(s, P4[sa.z * 4 + sl]);
            if (len > 3) s = f4add(s, P4[sa.w * 4 + sl]);
            if (len > 4) s = f4add(s, P4[sb.x * 4 + sl]);
            if (len > 5) s = f4add(s, P4[sb.y * 4 + sl]);
            if (len > 6) s = f4add(s, P4[sb.z * 4 + sl]);
            if (len > 7) s = f4add(s, P4[sb.w * 4 + sl]);

            const float inv = 1.0f / (float)len;
            a = f4fma(inv, s, a);
            a = f4fma(2.f, ((const float4*)cat_b)[sl], a);
            float4 t = f4add(PT4[ty * 4 + sl], ((const float4*)type_b)[sl]);

            float* row = stage + g * 36;
            ((float4*)row)[sl] = a;                    // cols 0..15
            row[19 + sl * 4 + 0] = t.x;                // cols 19..34
            row[19 + sl * 4 + 1] = t.y;
            row[19 + sl * 4 + 2] = t.z;
            row[19 + sl * 4 + 3] = t.w;
            if (sl == 0) {                             // cols 16..18
                row[16] = sent_t[(size_t)n * 3 + 0];
                row[17] = sent_t[(size_t)n * 3 + 1];
                row[18] = sent_t[(size_t)n * 3 + 2];
            }
        }
        __syncthreads();
        int rows = Nt - b * 64;
        if (rows > 64) rows = 64;
        const int cnt = rows * 35;
        const size_t base = (size_t)b * 64 * 35;
        for (int i = tid; i < cnt; i += 256) {
            const int r2 = i / 35;
            const int c2 = i - r2 * 35;
            out[base + i] = stage[r2 * 36 + c2];
        }
    } else {
        // ------------------------- history branch -------------------------
        if (tid < 192) {
            const int rr = tid >> 5, cc = tid & 31;
            const int srow = (rr < 3) ? (16 + rr) : (35 + (rr - 3));  // 16,17,18,35,36
            wl[tid] = (rr < 5) ? w1_W[srow * 32 + cc] : c0[cc];
        }
        __syncthreads();
        const int b2 = b - tb;
        const int g  = tid >> 3;       // 0..31: row within block
        const int sl = tid & 7;        // lane's float4 slot within the 32-col row
        const int n  = b2 * 32 + g;
        if (n < Nh) {
            const int cat = cat_h[n];
            const int ty  = type_h[n];
            int len = sub_len_h[n];
            if (len < 1) len = 1;
            const int4* sp = (const int4*)(sub_h + (size_t)n * 8);
            const int4 sa = sp[0];
            const int4 sb = sp[1];

            float4 q = Q4[cat * 8 + sl];
            float4 s = make_float4(0, 0, 0, 0);
            s = f4add(s, Q4[sa.x * 8 + sl]);
            if (len > 1) s = f4add(s, Q4[sa.y * 8 + sl]);
            if (len > 2) s = f4add(s, Q4[sa.z * 8 + sl]);
            if (len > 3) s = f4add(s, Q4[sa.w * 8 + sl]);
            if (len > 4) s = f4add(s, Q4[sb.x * 8 + sl]);
            if (len > 5) s = f4add(s, Q4[sb.y * 8 + sl]);
            if (len > 6) s = f4add(s, Q4[sb.z * 8 + sl]);
            if (len > 7) s = f4add(s, Q4[sb.w * 8 + sl]);

            const float inv = 1.0f / (float)len;
            q = f4fma(inv, s, q);
            q = f4add(q, QT4[ty * 8 + sl]);

            const float se0 = sent_h[(size_t)n * 3 + 0];
            const float se1 = sent_h[(size_t)n * 3 + 1];
            const float se2 = sent_h[(size_t)n * 3 + 2];
            const float rtv = rt_h[n];
            const float scv = sc_h[n];
            const float4* wl4 = (const float4*)wl;
            q = f4fma(se0, wl4[0 * 8 + sl], q);
            q = f4fma(se1, wl4[1 * 8 + sl], q);
            q = f4fma(se2, wl4[2 * 8 + sl], q);
            q = f4fma(rtv, wl4[3 * 8 + sl], q);
            q = f4fma(scv, wl4[4 * 8 + sl], q);
            q = f4add(q,   wl4[5 * 8 + sl]);

            float4* ob = (float4*)(out + (size_t)Nt * 35);
            ob[(size_t)n * 8 + sl] = q;               // coalesced 16B/lane
        }
    }
}

extern "C" void kernel_launch(void* const* d_in, const int* in_sizes, int n_in,
                              void* d_out, int out_size, void* d_ws, size_t ws_size,
                              hipStream_t stream) {
    const int*   cat_t     = (const int*)d_in[0];
    const int*   sub_t     = (const int*)d_in[1];
    const int*   sub_len_t = (const int*)d_in[2];
    const float* sent_t    = (const float*)d_in[3];
    const int*   type_t    = (const int*)d_in[4];
    const int*   cat_h     = (const int*)d_in[5];
    const int*   sub_h     = (const int*)d_in[6];
    const int*   sub_len_h = (const int*)d_in[7];
    const float* sent_h    = (const float*)d_in[8];
    const int*   type_h    = (const int*)d_in[9];
    const float* rt_h      = (const float*)d_in[10];
    const float* sc_h      = (const float*)d_in[11];
    const float* cat_emb   = (const float*)d_in[12];
    const float* cat_W     = (const float*)d_in[13];
    const float* cat_b     = (const float*)d_in[14];
    const float* type_emb  = (const float*)d_in[15];
    const float* type_W    = (const float*)d_in[16];
    const float* type_b    = (const float*)d_in[17];
    const float* w1_W      = (const float*)d_in[18];
    const float* w1_b      = (const float*)d_in[19];

    float* ws  = (float*)d_ws;
    float* out = (float*)d_out;
    const int Nt = in_sizes[0];
    const int Nh = in_sizes[5];

    precompute_tables<<<8, 128, 0, stream>>>(cat_emb, cat_W, cat_b,
                                             type_emb, type_W, type_b,
                                             w1_W, w1_b, ws);

    const int tbn = (Nt + 63) / 64;        // target blocks: 64 rows each
    const int hbn = (Nh + 31) / 32;        // history blocks: 32 rows each
    news_main<<<tbn + hbn, 256, 0, stream>>>(
        cat_t, sub_t, sub_len_t, sent_t, type_t,
        cat_h, sub_h, sub_len_h, sent_h, type_h,
        rt_h, sc_h, cat_b, type_b, w1_W,
        ws, out, Nt, Nh, tbn);
}

// Round 3
// 33.226 us; speedup vs baseline: 1.7060x; 1.3878x over previous
//
#include <hip/hip_runtime.h>

// ---------------------------------------------------------------------------
// NewsEncoder: fold all linear ops into gather tables (in d_ws).
//   P_cat  [1000][16] = cat_emb @ cat_W
//   P_type [10][16]   = type_emb @ type_W
//   Q_cat  [1000][32] = P_cat @ w1_W[0:16]
//   Q_type [10][32]   = P_type @ w1_W[19:35]
//   c0     [32]       = 2*cat_b@w1_W[0:16] + type_b@w1_W[19:35] + w1_b
// Target row:  x_t = [P_cat[cat]+mean(P_cat[sub])+2*cat_b, sent, P_type[ty]+type_b]
// History row: x_h = Q_cat[cat]+mean(Q_cat[sub])+Q_type[ty]
//                    + sent@w1_W[16:19] + rt*w1_W[35] + sc*w1_W[36] + c0
//
// R2 -> R3: persistent blocks. R1(10496 blk)=44us, R2(9216 blk)~35us with all
// pipes idle + occupancy 25% << static limit => workgroup dispatch-rate bound.
// Fix: 2048 grid-stride blocks (8/CU), inner tile bodies unchanged from R2.
// Also: precompute parallelized 16 waves -> 1024 waves (~6us -> ~1us).
// ---------------------------------------------------------------------------

#define OFF_PCAT  0
#define OFF_PTYPE 16000
#define OFF_QCAT  16384
#define OFF_QTYPE 48384
#define OFF_C0    48704

#define TBLK_T 256    // target blocks
#define TBLK_H 1792   // history blocks

__device__ __forceinline__ float4 f4add(float4 a, float4 b) {
    return make_float4(a.x + b.x, a.y + b.y, a.z + b.z, a.w + b.w);
}
__device__ __forceinline__ float4 f4fma(float s, float4 a, float4 c) {
    return make_float4(fmaf(s, a.x, c.x), fmaf(s, a.y, c.y),
                       fmaf(s, a.z, c.z), fmaf(s, a.w, c.w));
}

// ---------------------------------------------------------------------------
// Kernel A: build tables. 64 blocks x 256 threads; thread = (row r, col k).
// Block covers 16 table rows; rows 0..999 = cat, 1000..1009 = type.
// ---------------------------------------------------------------------------
__global__ __launch_bounds__(256) void precompute_tables(
    const float* __restrict__ cat_emb, const float* __restrict__ cat_W,
    const float* __restrict__ cat_b,   const float* __restrict__ type_emb,
    const float* __restrict__ type_W,  const float* __restrict__ type_b,
    const float* __restrict__ w1_W,    const float* __restrict__ w1_b,
    float* __restrict__ ws)
{
    __shared__ float sWc[64 * 16];
    __shared__ float sWt[64 * 16];
    __shared__ float sW1[37 * 32];
    __shared__ float sEmb[16][65];   // +1 pad breaks 16-way bank conflict
    __shared__ float sP[16][17];

    const int tid = threadIdx.x;
    for (int i = tid; i < 64 * 16; i += 256) { sWc[i] = cat_W[i]; sWt[i] = type_W[i]; }
    for (int i = tid; i < 37 * 32; i += 256) sW1[i] = w1_W[i];

    const int r   = tid >> 4;                 // 0..15 row-in-block
    const int k   = tid & 15;                 // 0..15 col
    const int row = blockIdx.x * 16 + r;
    const bool is_cat = (row < 1000);
    const bool valid  = (row < 1010);

    if (valid) {
        const float* src = is_cat ? (cat_emb + (size_t)row * 64)
                                  : (type_emb + (size_t)(row - 1000) * 64);
        const float4 v = ((const float4*)src)[k];     // k doubles as e4 index
        sEmb[r][k * 4 + 0] = v.x; sEmb[r][k * 4 + 1] = v.y;
        sEmb[r][k * 4 + 2] = v.z; sEmb[r][k * 4 + 3] = v.w;
    }
    __syncthreads();

    float p = 0.f;
    if (valid) {
        const float* sW = is_cat ? sWc : sWt;
#pragma unroll 8
        for (int e = 0; e < 64; ++e)
            p = fmaf(sEmb[r][e], sW[e * 16 + k], p);
        if (is_cat) ws[OFF_PCAT + row * 16 + k] = p;
        else        ws[OFF_PTYPE + (row - 1000) * 16 + k] = p;
    }
    sP[r][k] = p;
    __syncthreads();

    if (valid) {
        const int woff = is_cat ? 0 : 19;
        float q0 = 0.f, q1 = 0.f;
#pragma unroll
        for (int kk = 0; kk < 16; ++kk) {
            const float pv = sP[r][kk];
            q0 = fmaf(pv, sW1[(woff + kk) * 32 + k], q0);
            q1 = fmaf(pv, sW1[(woff + kk) * 32 + k + 16], q1);
        }
        if (is_cat) {
            ws[OFF_QCAT + row * 32 + k]      = q0;
            ws[OFF_QCAT + row * 32 + k + 16] = q1;
        } else {
            ws[OFF_QTYPE + (row - 1000) * 32 + k]      = q0;
            ws[OFF_QTYPE + (row - 1000) * 32 + k + 16] = q1;
        }
    }

    if (blockIdx.x == 0 && tid < 32) {
        float c = w1_b[tid];
#pragma unroll
        for (int kk = 0; kk < 16; ++kk) c = fmaf(2.f * cat_b[kk], sW1[kk * 32 + tid], c);
#pragma unroll
        for (int kk = 0; kk < 16; ++kk) c = fmaf(type_b[kk], sW1[(19 + kk) * 32 + tid], c);
        ws[OFF_C0 + tid] = c;
    }
}

// ---------------------------------------------------------------------------
// Kernel B: fused target + history, persistent grid-stride blocks.
//   blocks [0, TBLK_T):    target tiles (64 rows, 4 lanes/row, LDS-staged out)
//   blocks [TBLK_T, 2048): history tiles (32 rows, 8 lanes/row, direct f4 out)
// ---------------------------------------------------------------------------
__global__ __launch_bounds__(256, 8) void news_main(
    const int* __restrict__ cat_t, const int* __restrict__ sub_t,
    const int* __restrict__ sub_len_t, const float* __restrict__ sent_t,
    const int* __restrict__ type_t,
    const int* __restrict__ cat_h, const int* __restrict__ sub_h,
    const int* __restrict__ sub_len_h, const float* __restrict__ sent_h,
    const int* __restrict__ type_h,
    const float* __restrict__ rt_h, const float* __restrict__ sc_h,
    const float* __restrict__ cat_b, const float* __restrict__ type_b,
    const float* __restrict__ w1_W,
    const float* __restrict__ ws, float* __restrict__ out,
    int Nt, int Nh, int nTilesT, int nTilesH)
{
    __shared__ float stage[64 * 36];   // target out staging (9216 B)
    __shared__ float wl[6 * 32];       // history folded weights

    const float4* P4  = (const float4*)(ws + OFF_PCAT);   // [1000] rows of 4xf4
    const float4* PT4 = (const float4*)(ws + OFF_PTYPE);  // [10]   rows of 4xf4
    const float4* Q4  = (const float4*)(ws + OFF_QCAT);   // [1000] rows of 8xf4
    const float4* QT4 = (const float4*)(ws + OFF_QTYPE);  // [10]   rows of 8xf4
    const float*  c0  = ws + OFF_C0;

    const int tid = threadIdx.x;
    const int b   = blockIdx.x;

    if (b < TBLK_T) {
        // ------------------------- target branch -------------------------
        const int g  = tid >> 2;       // 0..63: row within tile
        const int sl = tid & 3;        // float4 slot within the 16-col row
        for (int tile = b; tile < nTilesT; tile += TBLK_T) {
            const int n = tile * 64 + g;
            if (n < Nt) {
                const int cat = cat_t[n];
                const int ty  = type_t[n];
                int len = sub_len_t[n];
                if (len < 1) len = 1;
                const int4* sp = (const int4*)(sub_t + (size_t)n * 8);
                const int4 sa = sp[0];
                const int4 sb = sp[1];

                float4 a = P4[cat * 4 + sl];
                float4 s = make_float4(0, 0, 0, 0);
                s = f4add(s, P4[sa.x * 4 + sl]);
                if (len > 1) s = f4add(s, P4[sa.y * 4 + sl]);
                if (len > 2) s = f4add(s, P4[sa.z * 4 + sl]);
                if (len > 3) s = f4add(s, P4[sa.w * 4 + sl]);
                if (len > 4) s = f4add(s, P4[sb.x * 4 + sl]);
                if (len > 5) s = f4add(s, P4[sb.y * 4 + sl]);
                if (len > 6) s = f4add(s, P4[sb.z * 4 + sl]);
                if (len > 7) s = f4add(s, P4[sb.w * 4 + sl]);

                const float inv = 1.0f / (float)len;
                a = f4fma(inv, s, a);
                a = f4fma(2.f, ((const float4*)cat_b)[sl], a);
                float4 t = f4add(PT4[ty * 4 + sl], ((const float4*)type_b)[sl]);

                float* row = stage + g * 36;
                ((float4*)row)[sl] = a;                    // cols 0..15
                row[19 + sl * 4 + 0] = t.x;                // cols 19..34
                row[19 + sl * 4 + 1] = t.y;
                row[19 + sl * 4 + 2] = t.z;
                row[19 + sl * 4 + 3] = t.w;
                if (sl == 0) {                             // cols 16..18
                    row[16] = sent_t[(size_t)n * 3 + 0];
                    row[17] = sent_t[(size_t)n * 3 + 1];
                    row[18] = sent_t[(size_t)n * 3 + 2];
                }
            }
            __syncthreads();
            int rows = Nt - tile * 64;
            if (rows > 64) rows = 64;
            const int cnt = rows * 35;
            const size_t base = (size_t)tile * 64 * 35;
            for (int i = tid; i < cnt; i += 256) {
                const int r2 = i / 35;
                const int c2 = i - r2 * 35;
                out[base + i] = stage[r2 * 36 + c2];
            }
            __syncthreads();   // stage reused next iteration
        }
    } else {
        // ------------------------- history branch -------------------------
        if (tid < 192) {
            const int rr = tid >> 5, cc = tid & 31;
            const int srow = (rr < 3) ? (16 + rr) : (35 + (rr - 3));  // 16,17,18,35,36
            wl[tid] = (rr < 5) ? w1_W[srow * 32 + cc] : c0[cc];
        }
        __syncthreads();
        const int g  = tid >> 3;       // 0..31: row within tile
        const int sl = tid & 7;        // float4 slot within the 32-col row
        float4* ob = (float4*)(out + (size_t)Nt * 35);
        const float4* wl4 = (const float4*)wl;

        for (int tile = b - TBLK_T; tile < nTilesH; tile += TBLK_H) {
            const int n = tile * 32 + g;
            if (n < Nh) {
                const int cat = cat_h[n];
                const int ty  = type_h[n];
                int len = sub_len_h[n];
                if (len < 1) len = 1;
                const int4* sp = (const int4*)(sub_h + (size_t)n * 8);
                const int4 sa = sp[0];
                const int4 sb = sp[1];

                float4 q = Q4[cat * 8 + sl];
                float4 s = make_float4(0, 0, 0, 0);
                s = f4add(s, Q4[sa.x * 8 + sl]);
                if (len > 1) s = f4add(s, Q4[sa.y * 8 + sl]);
                if (len > 2) s = f4add(s, Q4[sa.z * 8 + sl]);
                if (len > 3) s = f4add(s, Q4[sa.w * 8 + sl]);
                if (len > 4) s = f4add(s, Q4[sb.x * 8 + sl]);
                if (len > 5) s = f4add(s, Q4[sb.y * 8 + sl]);
                if (len > 6) s = f4add(s, Q4[sb.z * 8 + sl]);
                if (len > 7) s = f4add(s, Q4[sb.w * 8 + sl]);

                const float inv = 1.0f / (float)len;
                q = f4fma(inv, s, q);
                q = f4add(q, QT4[ty * 8 + sl]);

                const float se0 = sent_h[(size_t)n * 3 + 0];
                const float se1 = sent_h[(size_t)n * 3 + 1];
                const float se2 = sent_h[(size_t)n * 3 + 2];
                const float rtv = rt_h[n];
                const float scv = sc_h[n];
                q = f4fma(se0, wl4[0 * 8 + sl], q);
                q = f4fma(se1, wl4[1 * 8 + sl], q);
                q = f4fma(se2, wl4[2 * 8 + sl], q);
                q = f4fma(rtv, wl4[3 * 8 + sl], q);
                q = f4fma(scv, wl4[4 * 8 + sl], q);
                q = f4add(q,   wl4[5 * 8 + sl]);

                ob[(size_t)n * 8 + sl] = q;               // coalesced 16B/lane
            }
        }
    }
}

extern "C" void kernel_launch(void* const* d_in, const int* in_sizes, int n_in,
                              void* d_out, int out_size, void* d_ws, size_t ws_size,
                              hipStream_t stream) {
    const int*   cat_t     = (const int*)d_in[0];
    const int*   sub_t     = (const int*)d_in[1];
    const int*   sub_len_t = (const int*)d_in[2];
    const float* sent_t    = (const float*)d_in[3];
    const int*   type_t    = (const int*)d_in[4];
    const int*   cat_h     = (const int*)d_in[5];
    const int*   sub_h     = (const int*)d_in[6];
    const int*   sub_len_h = (const int*)d_in[7];
    const float* sent_h    = (const float*)d_in[8];
    const int*   type_h    = (const int*)d_in[9];
    const float* rt_h      = (const float*)d_in[10];
    const float* sc_h      = (const float*)d_in[11];
    const float* cat_emb   = (const float*)d_in[12];
    const float* cat_W     = (const float*)d_in[13];
    const float* cat_b     = (const float*)d_in[14];
    const float* type_emb  = (const float*)d_in[15];
    const float* type_W    = (const float*)d_in[16];
    const float* type_b    = (const float*)d_in[17];
    const float* w1_W      = (const float*)d_in[18];
    const float* w1_b      = (const float*)d_in[19];

    float* ws  = (float*)d_ws;
    float* out = (float*)d_out;
    const int Nt = in_sizes[0];
    const int Nh = in_sizes[5];

    precompute_tables<<<64, 256, 0, stream>>>(cat_emb, cat_W, cat_b,
                                              type_emb, type_W, type_b,
                                              w1_W, w1_b, ws);

    const int nTilesT = (Nt + 63) / 64;
    const int nTilesH = (Nh + 31) / 32;
    news_main<<<TBLK_T + TBLK_H, 256, 0, stream>>>(
        cat_t, sub_t, sub_len_t, sent_t, type_t,
        cat_h, sub_h, sub_len_h, sent_h, type_h,
        rt_h, sc_h, cat_b, type_b, w1_W,
        ws, out, Nt, Nh, nTilesT, nTilesH);
}

// Round 4
// 31.095 us; speedup vs baseline: 1.8229x; 1.0685x over previous
//
#include <hip/hip_runtime.h>

// ---------------------------------------------------------------------------
// NewsEncoder: fold all linear ops into gather tables (in d_ws).
//   P_cat  [1000][16] = cat_emb @ cat_W        (+ P_type [10][16])
//   Q_cat  [1000][32] = P_cat @ w1_W[0:16]     (+ Q_type [10][32])
//   c0     [32]       = 2*cat_b@w1_W[0:16] + type_b@w1_W[19:35] + w1_b
// Target row:  x_t = [P_cat[cat]+mean(P_cat[sub])+2*cat_b, sent, P_type[ty]+type_b]
// History row: x_h = Q_cat[cat]+mean(Q_cat[sub])+Q_type[ty]
//                    + sent@w1_W[16:19] + rt*w1_W[35] + sc*w1_W[36] + c0
//
// R3 -> R4: LDS-resident tables. Gathers were L2 round trips (192KB table
// > 32KB L1) in a dependent chain (index load -> gather) => latency-bound at
// ~15% HBM. Now: 256 blocks x 1024 threads (1/CU), table staged to LDS once,
// rows PADDED to odd f4 count (Q: 9xf4=144B, P: 5xf4=80B) so row-start banks
// form a perfect mod-8 partition -> conflict-free-ish LDS gathers.
// ---------------------------------------------------------------------------

#define OFF_PCAT  0
#define OFF_PTYPE 16000
#define OFF_QCAT  16384
#define OFF_QTYPE 48384
#define OFF_C0    48704

#define HBLK 200            // history blocks
#define TBLK 56             // target blocks
#define SMEM_FLOATS 36552   // max(history 36552, target 29416) floats

__device__ __forceinline__ float4 f4add(float4 a, float4 b) {
    return make_float4(a.x + b.x, a.y + b.y, a.z + b.z, a.w + b.w);
}
__device__ __forceinline__ float4 f4fma(float s, float4 a, float4 c) {
    return make_float4(fmaf(s, a.x, c.x), fmaf(s, a.y, c.y),
                       fmaf(s, a.z, c.z), fmaf(s, a.w, c.w));
}

// ---------------------------------------------------------------------------
// Kernel A: build tables. 64 blocks x 256 threads; thread = (row r, col k).
// ---------------------------------------------------------------------------
__global__ __launch_bounds__(256) void precompute_tables(
    const float* __restrict__ cat_emb, const float* __restrict__ cat_W,
    const float* __restrict__ cat_b,   const float* __restrict__ type_emb,
    const float* __restrict__ type_W,  const float* __restrict__ type_b,
    const float* __restrict__ w1_W,    const float* __restrict__ w1_b,
    float* __restrict__ ws)
{
    __shared__ float sWc[64 * 16];
    __shared__ float sWt[64 * 16];
    __shared__ float sW1[37 * 32];
    __shared__ float sEmb[16][65];
    __shared__ float sP[16][17];

    const int tid = threadIdx.x;
    for (int i = tid; i < 64 * 16; i += 256) { sWc[i] = cat_W[i]; sWt[i] = type_W[i]; }
    for (int i = tid; i < 37 * 32; i += 256) sW1[i] = w1_W[i];

    const int r   = tid >> 4;
    const int k   = tid & 15;
    const int row = blockIdx.x * 16 + r;
    const bool is_cat = (row < 1000);
    const bool valid  = (row < 1010);

    if (valid) {
        const float* src = is_cat ? (cat_emb + (size_t)row * 64)
                                  : (type_emb + (size_t)(row - 1000) * 64);
        const float4 v = ((const float4*)src)[k];
        sEmb[r][k * 4 + 0] = v.x; sEmb[r][k * 4 + 1] = v.y;
        sEmb[r][k * 4 + 2] = v.z; sEmb[r][k * 4 + 3] = v.w;
    }
    __syncthreads();

    float p = 0.f;
    if (valid) {
        const float* sW = is_cat ? sWc : sWt;
#pragma unroll 8
        for (int e = 0; e < 64; ++e)
            p = fmaf(sEmb[r][e], sW[e * 16 + k], p);
        if (is_cat) ws[OFF_PCAT + row * 16 + k] = p;
        else        ws[OFF_PTYPE + (row - 1000) * 16 + k] = p;
    }
    sP[r][k] = p;
    __syncthreads();

    if (valid) {
        const int woff = is_cat ? 0 : 19;
        float q0 = 0.f, q1 = 0.f;
#pragma unroll
        for (int kk = 0; kk < 16; ++kk) {
            const float pv = sP[r][kk];
            q0 = fmaf(pv, sW1[(woff + kk) * 32 + k], q0);
            q1 = fmaf(pv, sW1[(woff + kk) * 32 + k + 16], q1);
        }
        if (is_cat) {
            ws[OFF_QCAT + row * 32 + k]      = q0;
            ws[OFF_QCAT + row * 32 + k + 16] = q1;
        } else {
            ws[OFF_QTYPE + (row - 1000) * 32 + k]      = q0;
            ws[OFF_QTYPE + (row - 1000) * 32 + k + 16] = q1;
        }
    }

    if (blockIdx.x == 0 && tid < 32) {
        float c = w1_b[tid];
#pragma unroll
        for (int kk = 0; kk < 16; ++kk) c = fmaf(2.f * cat_b[kk], sW1[kk * 32 + tid], c);
#pragma unroll
        for (int kk = 0; kk < 16; ++kk) c = fmaf(type_b[kk], sW1[(19 + kk) * 32 + tid], c);
        ws[OFF_C0 + tid] = c;
    }
}

// ---------------------------------------------------------------------------
// Kernel B: 256 blocks x 1024 threads, 1 block/CU, LDS-resident tables.
//   blocks [0, HBLK):         history, 128 rows/tile, 8 lanes/row
//   blocks [HBLK, HBLK+TBLK): target, 256 rows/tile, 4 lanes/row
// ---------------------------------------------------------------------------
__global__ __launch_bounds__(1024, 4) void news_main(
    const int* __restrict__ cat_t, const int* __restrict__ sub_t,
    const int* __restrict__ sub_len_t, const float* __restrict__ sent_t,
    const int* __restrict__ type_t,
    const int* __restrict__ cat_h, const int* __restrict__ sub_h,
    const int* __restrict__ sub_len_h, const float* __restrict__ sent_h,
    const int* __restrict__ type_h,
    const float* __restrict__ rt_h, const float* __restrict__ sc_h,
    const float* __restrict__ cat_b, const float* __restrict__ type_b,
    const float* __restrict__ w1_W,
    const float* __restrict__ ws, float* __restrict__ out,
    int Nt, int Nh, int nTilesT, int nTilesH)
{
    __shared__ float smem[SMEM_FLOATS];

    const int tid = threadIdx.x;
    const int b   = blockIdx.x;

    if (b < HBLK) {
        // ------------------------- history branch -------------------------
        // LDS layout: lq [1000][9xf4] pad | lqt [10][9xf4] pad | wl [6][32]
        float4* lq4  = (float4*)smem;
        float4* lqt4 = (float4*)(smem + 36000);
        float*  wl   = smem + 36360;

        const float4* Qs  = (const float4*)(ws + OFF_QCAT);
        const float4* QTs = (const float4*)(ws + OFF_QTYPE);
        for (int i = tid; i < 8000; i += 1024) {
            const int r = i >> 3, j = i & 7;
            lq4[r * 9 + j] = Qs[i];
        }
        if (tid < 80) {
            const int r = tid >> 3, j = tid & 7;
            lqt4[r * 9 + j] = QTs[tid];
        }
        if (tid < 192) {
            const int rr = tid >> 5, cc = tid & 31;
            const int srow = (rr < 3) ? (16 + rr) : (35 + (rr - 3));  // 16,17,18,35,36
            wl[tid] = (rr < 5) ? w1_W[srow * 32 + cc] : ws[OFF_C0 + cc];
        }
        __syncthreads();

        const int g  = tid >> 3;       // 0..127: row within tile
        const int sl = tid & 7;        // float4 slot within the 32-col row
        float4* ob = (float4*)(out + (size_t)Nt * 35);
        const float4* wl4 = (const float4*)wl;

        for (int tile = b; tile < nTilesH; tile += HBLK) {
            const int n = tile * 128 + g;
            if (n < Nh) {
                const int cat = cat_h[n];
                const int ty  = type_h[n];
                int len = sub_len_h[n];
                if (len < 1) len = 1;
                const int4* sp = (const int4*)(sub_h + (size_t)n * 8);
                const int4 sa = sp[0];
                const int4 sb = sp[1];

                float4 q = lq4[cat * 9 + sl];
                float4 s = make_float4(0, 0, 0, 0);
                s = f4add(s, lq4[sa.x * 9 + sl]);
                if (len > 1) s = f4add(s, lq4[sa.y * 9 + sl]);
                if (len > 2) s = f4add(s, lq4[sa.z * 9 + sl]);
                if (len > 3) s = f4add(s, lq4[sa.w * 9 + sl]);
                if (len > 4) s = f4add(s, lq4[sb.x * 9 + sl]);
                if (len > 5) s = f4add(s, lq4[sb.y * 9 + sl]);
                if (len > 6) s = f4add(s, lq4[sb.z * 9 + sl]);
                if (len > 7) s = f4add(s, lq4[sb.w * 9 + sl]);

                const float inv = 1.0f / (float)len;
                q = f4fma(inv, s, q);
                q = f4add(q, lqt4[ty * 9 + sl]);

                const float se0 = sent_h[(size_t)n * 3 + 0];
                const float se1 = sent_h[(size_t)n * 3 + 1];
                const float se2 = sent_h[(size_t)n * 3 + 2];
                const float rtv = rt_h[n];
                const float scv = sc_h[n];
                q = f4fma(se0, wl4[0 * 8 + sl], q);
                q = f4fma(se1, wl4[1 * 8 + sl], q);
                q = f4fma(se2, wl4[2 * 8 + sl], q);
                q = f4fma(rtv, wl4[3 * 8 + sl], q);
                q = f4fma(scv, wl4[4 * 8 + sl], q);
                q = f4add(q,   wl4[5 * 8 + sl]);

                ob[(size_t)n * 8 + sl] = q;               // coalesced 16B/lane
            }
        }
    } else {
        // ------------------------- target branch -------------------------
        // LDS layout: lp [1000][5xf4] pad | lpt [10][5xf4] pad | stage [256][36]
        float4* lp4   = (float4*)smem;
        float4* lpt4  = (float4*)(smem + 20000);
        float*  stage = smem + 20200;

        const float4* Ps  = (const float4*)(ws + OFF_PCAT);
        const float4* PTs = (const float4*)(ws + OFF_PTYPE);
        for (int i = tid; i < 4000; i += 1024) {
            const int r = i >> 2, j = i & 3;
            lp4[r * 5 + j] = Ps[i];
        }
        if (tid < 40) {
            const int r = tid >> 2, j = tid & 3;
            lpt4[r * 5 + j] = PTs[tid];
        }
        __syncthreads();

        const int g  = tid >> 2;       // 0..255: row within tile
        const int sl = tid & 3;        // float4 slot within the 16-col row

        for (int tile = b - HBLK; tile < nTilesT; tile += TBLK) {
            const int n = tile * 256 + g;
            if (n < Nt) {
                const int cat = cat_t[n];
                const int ty  = type_t[n];
                int len = sub_len_t[n];
                if (len < 1) len = 1;
                const int4* sp = (const int4*)(sub_t + (size_t)n * 8);
                const int4 sa = sp[0];
                const int4 sb = sp[1];

                float4 a = lp4[cat * 5 + sl];
                float4 s = make_float4(0, 0, 0, 0);
                s = f4add(s, lp4[sa.x * 5 + sl]);
                if (len > 1) s = f4add(s, lp4[sa.y * 5 + sl]);
                if (len > 2) s = f4add(s, lp4[sa.z * 5 + sl]);
                if (len > 3) s = f4add(s, lp4[sa.w * 5 + sl]);
                if (len > 4) s = f4add(s, lp4[sb.x * 5 + sl]);
                if (len > 5) s = f4add(s, lp4[sb.y * 5 + sl]);
                if (len > 6) s = f4add(s, lp4[sb.z * 5 + sl]);
                if (len > 7) s = f4add(s, lp4[sb.w * 5 + sl]);

                const float inv = 1.0f / (float)len;
                a = f4fma(inv, s, a);
                a = f4fma(2.f, ((const float4*)cat_b)[sl], a);
                float4 t = f4add(lpt4[ty * 5 + sl], ((const float4*)type_b)[sl]);

                float* row = stage + g * 36;
                ((float4*)row)[sl] = a;                    // cols 0..15
                row[19 + sl * 4 + 0] = t.x;                // cols 19..34
                row[19 + sl * 4 + 1] = t.y;
                row[19 + sl * 4 + 2] = t.z;
                row[19 + sl * 4 + 3] = t.w;
                if (sl == 0) {                             // cols 16..18
                    row[16] = sent_t[(size_t)n * 3 + 0];
                    row[17] = sent_t[(size_t)n * 3 + 1];
                    row[18] = sent_t[(size_t)n * 3 + 2];
                }
            }
            __syncthreads();
            int rows = Nt - tile * 256;
            if (rows > 256) rows = 256;
            const int cnt = rows * 35;
            const size_t base = (size_t)tile * 256 * 35;
            for (int i = tid; i < cnt; i += 1024) {
                const int r2 = i / 35;
                const int c2 = i - r2 * 35;
                out[base + i] = stage[r2 * 36 + c2];
            }
            __syncthreads();   // stage reused next iteration
        }
    }
}

extern "C" void kernel_launch(void* const* d_in, const int* in_sizes, int n_in,
                              void* d_out, int out_size, void* d_ws, size_t ws_size,
                              hipStream_t stream) {
    const int*   cat_t     = (const int*)d_in[0];
    const int*   sub_t     = (const int*)d_in[1];
    const int*   sub_len_t = (const int*)d_in[2];
    const float* sent_t    = (const float*)d_in[3];
    const int*   type_t    = (const int*)d_in[4];
    const int*   cat_h     = (const int*)d_in[5];
    const int*   sub_h     = (const int*)d_in[6];
    const int*   sub_len_h = (const int*)d_in[7];
    const float* sent_h    = (const float*)d_in[8];
    const int*   type_h    = (const int*)d_in[9];
    const float* rt_h      = (const float*)d_in[10];
    const float* sc_h      = (const float*)d_in[11];
    const float* cat_emb   = (const float*)d_in[12];
    const float* cat_W     = (const float*)d_in[13];
    const float* cat_b     = (const float*)d_in[14];
    const float* type_emb  = (const float*)d_in[15];
    const float* type_W    = (const float*)d_in[16];
    const float* type_b    = (const float*)d_in[17];
    const float* w1_W      = (const float*)d_in[18];
    const float* w1_b      = (const float*)d_in[19];

    float* ws  = (float*)d_ws;
    float* out = (float*)d_out;
    const int Nt = in_sizes[0];
    const int Nh = in_sizes[5];

    precompute_tables<<<64, 256, 0, stream>>>(cat_emb, cat_W, cat_b,
                                              type_emb, type_W, type_b,
                                              w1_W, w1_b, ws);

    const int nTilesT = (Nt + 255) / 256;
    const int nTilesH = (Nh + 127) / 128;
    news_main<<<HBLK + TBLK, 1024, 0, stream>>>(
        cat_t, sub_t, sub_len_t, sent_t, type_t,
        cat_h, sub_h, sub_len_h, sent_h, type_h,
        rt_h, sc_h, cat_b, type_b, w1_W,
        ws, out, Nt, Nh, nTilesT, nTilesH);
}